// Round 7
// baseline (411.173 us; speedup 1.0000x reference)
//
#include <hip/hip_runtime.h>
#include <hip/hip_bf16.h>

#define NB 16
#define NC 64

static __device__ __forceinline__ unsigned short f2bfr(float f) {
    union { float f; unsigned u; } cv; cv.f = f;
    unsigned r = cv.u + 0x7fffu + ((cv.u >> 16) & 1u);
    return (unsigned short)(r >> 16);
}
static __device__ __forceinline__ float bfr2f(unsigned short h) {
    union { unsigned u; float f; } cv; cv.u = ((unsigned)h) << 16;
    return cv.f;
}
static __device__ __forceinline__ unsigned pack2bf(float lo, float hi) {
    return ((unsigned)f2bfr(lo)) | (((unsigned)f2bfr(hi)) << 16);
}

// ---------------------------------------------------------------------------
// Shift-addressed float4 staging of a 68x76-stride halo tile (start row sTop,
// col sLeft; sLeft 4-aligned). Zero-fills out-of-range float4s. 72 data cols.
// ---------------------------------------------------------------------------
template <int H>
static __device__ __forceinline__ void stage_tile(
    const float* __restrict__ src, size_t ibase, int sTop, int sLeft,
    float (*sIn)[76], int tid)
{
#pragma unroll
    for (int i = 0; i < 5; ++i) {
        int idx = i * 256 + tid;
        if (idx < 68 * 16) {
            int r = idx >> 4, c4 = (idx & 15) << 2;
            int gy = sTop + r, gx = sLeft + c4;
            float4 v = make_float4(0.f, 0.f, 0.f, 0.f);
            if ((unsigned)gy < (unsigned)H && (unsigned)gx < (unsigned)H)
                v = *(const float4*)(src + ibase + (size_t)gy * H + gx);
            *(float4*)(&sIn[r][c4]) = v;
        }
    }
    if (tid < 136) {
        int r = tid >> 1, c4 = 64 + ((tid & 1) << 2);
        int gy = sTop + r, gx = sLeft + c4;
        float4 v = make_float4(0.f, 0.f, 0.f, 0.f);
        if ((unsigned)gy < (unsigned)H && (unsigned)gx < (unsigned)H)
            v = *(const float4*)(src + ibase + (size_t)gy * H + gx);
        *(float4*)(&sIn[r][c4]) = v;
    }
}

// ---------------------------------------------------------------------------
// K1: LL band of Haar DWT of x: (B,C,256,256) -> (B,C,128,128). Pure stream.
// ---------------------------------------------------------------------------
__global__ __launch_bounds__(256) void ll_kernel(
    const float* __restrict__ in, float* __restrict__ ll)
{
    int t = blockIdx.x * 256 + threadIdx.x;
    int jp  = t & 63;
    int i   = (t >> 6) & 127;
    int img = t >> 13;
    size_t ib = (size_t)img * 65536;
    float4 a = *(const float4*)(in + ib + (size_t)(2 * i) * 256 + 4 * jp);
    float4 b = *(const float4*)(in + ib + (size_t)(2 * i + 1) * 256 + 4 * jp);
    float2 o;
    o.x = 0.5f * (a.x + a.y + b.x + b.y);
    o.y = 0.5f * (a.z + a.w + b.z + b.w);
    *(float2*)(ll + (size_t)img * 16384 + (size_t)i * 128 + 2 * jp) = o;
}

// ---------------------------------------------------------------------------
// K2/K3: fused Haar DWT + depthwise 3x3 conv + scale. 2x2 outputs/thread,
// shared register DWT (8x8 patch -> 16 DWT positions -> 4 outputs x 4 bands).
// in (B,C,H,H) fp32 -> t (B,C,4,H/2,H/2) BF16, curn fp32 = pre-conv LL.
// ---------------------------------------------------------------------------
template <int H>
__global__ __launch_bounds__(256) void dwt_conv_kernel(
    const float* __restrict__ in, const float* __restrict__ ww,
    const float* __restrict__ wsc, unsigned short* __restrict__ t_out,
    float* __restrict__ curn)
{
    constexpr int H2 = H / 2;
    constexpr int TX = H2 / 32;
    const int tile = blockIdx.x;
    const int c = blockIdx.y, b = blockIdx.z;
    const int ty = tile / TX, tx = tile % TX;
    const int oy0 = ty * 32, ox0 = tx * 32;
    const int tid = threadIdx.x;
    const int qi = 2 * (tid >> 4), qj = 2 * (tid & 15);

    __shared__ float sIn[68][76];

    float w[4][9], sc[4];
#pragma unroll
    for (int k = 0; k < 4; ++k) {
#pragma unroll
        for (int i = 0; i < 9; ++i) w[k][i] = ww[(c * 4 + k) * 9 + i];
        sc[k] = 0.5f * wsc[c * 4 + k];   // fold DWT 0.5
    }

    const size_t ibase = (size_t)(b * NC + c) * H * H;
    stage_tile<H>(in, ibase, 2 * oy0 - 2, 2 * ox0 - 4, sIn, tid);
    __syncthreads();

    float kk[4][4];   // [band][2*mi+mj]
#pragma unroll
    for (int i = 0; i < 4; ++i)
#pragma unroll
        for (int j = 0; j < 4; ++j) kk[i][j] = 0.f;
    float llc[4];

    const int pr0 = 2 * qi, pc0 = 2 * qj + 2;   // patch origin in sIn
#pragma unroll
    for (int rp = 0; rp < 4; ++rp) {
        float xa[8], xb[8];
#pragma unroll
        for (int n = 0; n < 4; ++n) {
            float2 va = *(const float2*)&sIn[pr0 + 2 * rp][pc0 + 2 * n];
            float2 vb = *(const float2*)&sIn[pr0 + 2 * rp + 1][pc0 + 2 * n];
            xa[2 * n] = va.x; xa[2 * n + 1] = va.y;
            xb[2 * n] = vb.x; xb[2 * n + 1] = vb.y;
        }
        float D0[4], D1[4], D2[4], D3[4];
#pragma unroll
        for (int n = 0; n < 4; ++n) {
            float a = xa[2 * n], e = xa[2 * n + 1];
            float f = xb[2 * n], g = xb[2 * n + 1];
            float s0 = a + e, s1 = f + g, d0 = a - e, d1 = f - g;
            D0[n] = s0 + s1; D1[n] = s0 - s1;
            D2[n] = d0 + d1; D3[n] = d0 - d1;
        }
#pragma unroll
        for (int mi = 0; mi < 2; ++mi) {
            const int r = rp - mi;
            if (r >= 0 && r <= 2) {
#pragma unroll
                for (int mj = 0; mj < 2; ++mj) {
                    const int m = 2 * mi + mj;
#pragma unroll
                    for (int s = 0; s < 3; ++s) {
                        kk[0][m] = fmaf(w[0][3 * r + s], D0[mj + s], kk[0][m]);
                        kk[1][m] = fmaf(w[1][3 * r + s], D1[mj + s], kk[1][m]);
                        kk[2][m] = fmaf(w[2][3 * r + s], D2[mj + s], kk[2][m]);
                        kk[3][m] = fmaf(w[3][3 * r + s], D3[mj + s], kk[3][m]);
                    }
                }
                if (r == 1) {   // rp = mi+1: quad-center DWT row
                    llc[2 * mi + 0] = 0.5f * D0[1];
                    llc[2 * mi + 1] = 0.5f * D0[2];
                }
            }
        }
    }

    const size_t tbase = (size_t)(b * NC + c) * 4 * H2 * H2;
    const size_t o00 = (size_t)(oy0 + qi) * H2 + (ox0 + qj);
#pragma unroll
    for (int band = 0; band < 4; ++band) {
        size_t bo = tbase + (size_t)band * H2 * H2 + o00;
#pragma unroll
        for (int mi = 0; mi < 2; ++mi)
            *(unsigned*)(t_out + bo + (size_t)mi * H2) =
                pack2bf(kk[band][2 * mi] * sc[band], kk[band][2 * mi + 1] * sc[band]);
    }
    if (curn) {
        const size_t cbase = (size_t)(b * NC + c) * H2 * H2 + o00;
        *(float2*)(curn + cbase)      = make_float2(llc[0], llc[1]);
        *(float2*)(curn + cbase + H2) = make_float2(llc[2], llc[3]);
    }
}

// ---------------------------------------------------------------------------
// K6: final fuse. Register DWT (shared across 2x2 quads) -> band convs ->
// inline 2-level IDWT recon from t1/t2 (bf16) -> + base conv -> y (bf16) +
// deterministic BN partials. 64x64 pixel tile, 256 threads, 4x4 px/thread.
// ---------------------------------------------------------------------------
__global__ __launch_bounds__(256) void final_fuse_kernel(
    const float* __restrict__ x, const unsigned short* __restrict__ t1,
    const unsigned short* __restrict__ t2, const float* __restrict__ bw,
    const float* __restrict__ bb, const float* __restrict__ bs,
    const float* __restrict__ ww0, const float* __restrict__ ws0,
    unsigned short* __restrict__ ybf, float2* __restrict__ partials)
{
    const int tile = blockIdx.x, c = blockIdx.y, b = blockIdx.z;
    const int ty = tile >> 2, tx = tile & 3;
    const int oy0 = ty * 64, ox0 = tx * 64;
    const int tid = threadIdx.x;
    const int qi = 2 * (tid >> 4), qj = 2 * (tid & 15);

    __shared__ float sIn[68][76];
    __shared__ float rS[256], rQ[256];

    float w[4][9], sc[4], wb[9];
#pragma unroll
    for (int k = 0; k < 4; ++k) {
#pragma unroll
        for (int i = 0; i < 9; ++i) w[k][i] = ww0[(c * 4 + k) * 9 + i];
        sc[k] = 0.25f * ws0[c * 4 + k];   // DWT 0.5 x IDWT 0.5
    }
#pragma unroll
    for (int i = 0; i < 9; ++i) wb[i] = bw[c * 9 + i];
    const float scale = bs[c];
    const float bsc = bb[c] * scale;

    const size_t xb = (size_t)(b * NC + c) * 65536;
    stage_tile<256>(x, xb, oy0 - 2, ox0 - 4, sIn, tid);

    // --- two-level IDWT recon: one t1 pos, one t2 pos per thread (pre-sync,
    // global loads overlap LDS staging) ---
    const int i1 = ty * 16 + (tid >> 4);   // t1 row (64-grid)
    const int j1 = tx * 16 + (tid & 15);   // t1 col
    const size_t img = (size_t)(b * NC + c);
    const size_t t1b = img * 16384 + (size_t)i1 * 64 + j1;
    const size_t t2b = img * 4096 + (size_t)(i1 >> 1) * 32 + (j1 >> 1);
    float m0 = bfr2f(t2[t2b]);
    float m1 = bfr2f(t2[t2b + 1024]);
    float m2 = bfr2f(t2[t2b + 2048]);
    float m3 = bfr2f(t2[t2b + 3072]);
    float a1 = (i1 & 1) ? -m1 : m1;
    float a2 = (j1 & 1) ? -m2 : m2;
    float a3 = ((i1 ^ j1) & 1) ? -m3 : m3;
    float k0 = bfr2f(t1[t1b]) + 0.5f * (m0 + a1 + a2 + a3);
    float k1 = bfr2f(t1[t1b + 4096]);
    float k2 = bfr2f(t1[t1b + 8192]);
    float k3 = bfr2f(t1[t1b + 12288]);
    float nxtq[2][2];   // 0.25 = idwt(t1) 0.5 x K6-idwt LL 0.5
    nxtq[0][0] = 0.25f * (k0 + k1 + k2 + k3);
    nxtq[0][1] = 0.25f * (k0 + k1 - k2 - k3);
    nxtq[1][0] = 0.25f * (k0 - k1 + k2 - k3);
    nxtq[1][1] = 0.25f * (k0 - k1 - k2 + k3);

    __syncthreads();

    float kk[4][4];
#pragma unroll
    for (int i = 0; i < 4; ++i)
#pragma unroll
        for (int j = 0; j < 4; ++j) kk[i][j] = 0.f;
    float acc[4][4];
#pragma unroll
    for (int i = 0; i < 4; ++i)
#pragma unroll
        for (int j = 0; j < 4; ++j) acc[i][j] = 0.f;

    const int pr0 = 2 * qi, pc0 = 2 * qj + 2;
#pragma unroll
    for (int rp = 0; rp < 4; ++rp) {
        float xa[8], xb8[8];
#pragma unroll
        for (int n = 0; n < 4; ++n) {
            float2 va = *(const float2*)&sIn[pr0 + 2 * rp][pc0 + 2 * n];
            float2 vb = *(const float2*)&sIn[pr0 + 2 * rp + 1][pc0 + 2 * n];
            xa[2 * n] = va.x; xa[2 * n + 1] = va.y;
            xb8[2 * n] = vb.x; xb8[2 * n + 1] = vb.y;
        }
        float D0[4], D1[4], D2[4], D3[4];
#pragma unroll
        for (int n = 0; n < 4; ++n) {
            float a = xa[2 * n], e = xa[2 * n + 1];
            float f = xb8[2 * n], g = xb8[2 * n + 1];
            float s0 = a + e, s1 = f + g, d0 = a - e, d1 = f - g;
            D0[n] = s0 + s1; D1[n] = s0 - s1;
            D2[n] = d0 + d1; D3[n] = d0 - d1;
        }
#pragma unroll
        for (int mi = 0; mi < 2; ++mi) {
            const int r = rp - mi;
            if (r >= 0 && r <= 2) {
#pragma unroll
                for (int mj = 0; mj < 2; ++mj) {
                    const int m = 2 * mi + mj;
#pragma unroll
                    for (int s = 0; s < 3; ++s) {
                        kk[0][m] = fmaf(w[0][3 * r + s], D0[mj + s], kk[0][m]);
                        kk[1][m] = fmaf(w[1][3 * r + s], D1[mj + s], kk[1][m]);
                        kk[2][m] = fmaf(w[2][3 * r + s], D2[mj + s], kk[2][m]);
                        kk[3][m] = fmaf(w[3][3 * r + s], D3[mj + s], kk[3][m]);
                    }
                }
            }
        }
        // base conv contributions from patch rows 2rp and 2rp+1
#pragma unroll
        for (int half = 0; half < 2; ++half) {
            const int kr = 2 * rp + half;
#pragma unroll
            for (int p = 0; p < 4; ++p) {
                const int rr = kr - 1 - p;
                if (rr >= 0 && rr < 3) {
#pragma unroll
                    for (int u = 0; u < 4; ++u) {
                        float t = half ? (xb8[u + 1] * wb[3 * rr] +
                                          xb8[u + 2] * wb[3 * rr + 1] +
                                          xb8[u + 3] * wb[3 * rr + 2])
                                       : (xa[u + 1] * wb[3 * rr] +
                                          xa[u + 2] * wb[3 * rr + 1] +
                                          xa[u + 3] * wb[3 * rr + 2]);
                        acc[p][u] += t;
                    }
                }
            }
        }
    }

    // epilogue: per-quad IDWT + base path, pack to bf16, stats
    float val[4][4];
    float lsum = 0.f, lss = 0.f;
#pragma unroll
    for (int mi = 0; mi < 2; ++mi)
#pragma unroll
        for (int mj = 0; mj < 2; ++mj) {
            const int m = 2 * mi + mj;
            float c0 = fmaf(kk[0][m], sc[0], nxtq[mi][mj]);
            float c1 = kk[1][m] * sc[1];
            float c2 = kk[2][m] * sc[2];
            float c3 = kk[3][m] * sc[3];
            float vv00 = c0 + c1 + c2 + c3;
            float vv01 = c0 + c1 - c2 - c3;
            float vv10 = c0 - c1 + c2 - c3;
            float vv11 = c0 - c1 - c2 + c3;
            val[2 * mi + 0][2 * mj + 0] = fmaf(acc[2 * mi + 0][2 * mj + 0], scale, bsc) + vv00;
            val[2 * mi + 0][2 * mj + 1] = fmaf(acc[2 * mi + 0][2 * mj + 1], scale, bsc) + vv01;
            val[2 * mi + 1][2 * mj + 0] = fmaf(acc[2 * mi + 1][2 * mj + 0], scale, bsc) + vv10;
            val[2 * mi + 1][2 * mj + 1] = fmaf(acc[2 * mi + 1][2 * mj + 1], scale, bsc) + vv11;
        }
#pragma unroll
    for (int p = 0; p < 4; ++p) {
#pragma unroll
        for (int u = 0; u < 4; ++u) {
            lsum += val[p][u];
            lss = fmaf(val[p][u], val[p][u], lss);
        }
        uint2 st;
        st.x = pack2bf(val[p][0], val[p][1]);
        st.y = pack2bf(val[p][2], val[p][3]);
        *(uint2*)(ybf + xb + (size_t)(oy0 + 2 * qi + p) * 256 + (ox0 + 2 * qj)) = st;
    }

    rS[tid] = lsum;
    rQ[tid] = lss;
    __syncthreads();
    for (int off = 128; off > 0; off >>= 1) {
        if (tid < off) { rS[tid] += rS[tid + off]; rQ[tid] += rQ[tid + off]; }
        __syncthreads();
    }
    if (tid == 0)
        partials[c * 256 + b * 16 + tile] = make_float2(rS[0], rQ[0]);
}

// ---------------------------------------------------------------------------
// K7: per-channel BN stats -> (a,b). 64 blocks x 256 threads.
// ---------------------------------------------------------------------------
__global__ __launch_bounds__(256) void stats_kernel(
    const float2* __restrict__ partials, const float* __restrict__ gamma,
    const float* __restrict__ beta, float2* __restrict__ ab)
{
    const int c = blockIdx.x;
    const int tid = threadIdx.x;
    __shared__ float s1[256], s2[256];
    float2 p = partials[c * 256 + tid];
    s1[tid] = p.x;
    s2[tid] = p.y;
    __syncthreads();
    for (int off = 128; off > 0; off >>= 1) {
        if (tid < off) { s1[tid] += s1[tid + off]; s2[tid] += s2[tid + off]; }
        __syncthreads();
    }
    if (tid == 0) {
        const float N = (float)NB * 65536.0f;
        float mean = s1[0] / N;
        float var = s2[0] / N - mean * mean;
        float inv = rsqrtf(var + 1e-5f);
        float a = gamma[c] * inv;
        ab[c] = make_float2(a, beta[c] - mean * a);
    }
}

// ---------------------------------------------------------------------------
// K8: normalize + ReLU: bf16 y-staging -> fp32 d_out. 8 elems per iter.
// ---------------------------------------------------------------------------
__global__ __launch_bounds__(256) void norm_out_kernel(
    const unsigned short* __restrict__ ybf, const float2* __restrict__ ab,
    float* __restrict__ out)
{
    const long total8 = (long)NB * NC * 65536 / 8;
    const long stride = (long)gridDim.x * 256;
    for (long i = blockIdx.x * 256L + threadIdx.x; i < total8; i += stride) {
        long e = i * 8;
        int c = (int)((e >> 16) & (NC - 1));
        float2 s = ab[c];
        uint4 v = *(const uint4*)(ybf + e);
        float4 o0, o1;
        o0.x = fmaxf(fmaf(bfr2f((unsigned short)(v.x & 0xffff)), s.x, s.y), 0.f);
        o0.y = fmaxf(fmaf(bfr2f((unsigned short)(v.x >> 16)),    s.x, s.y), 0.f);
        o0.z = fmaxf(fmaf(bfr2f((unsigned short)(v.y & 0xffff)), s.x, s.y), 0.f);
        o0.w = fmaxf(fmaf(bfr2f((unsigned short)(v.y >> 16)),    s.x, s.y), 0.f);
        o1.x = fmaxf(fmaf(bfr2f((unsigned short)(v.z & 0xffff)), s.x, s.y), 0.f);
        o1.y = fmaxf(fmaf(bfr2f((unsigned short)(v.z >> 16)),    s.x, s.y), 0.f);
        o1.z = fmaxf(fmaf(bfr2f((unsigned short)(v.w & 0xffff)), s.x, s.y), 0.f);
        o1.w = fmaxf(fmaf(bfr2f((unsigned short)(v.w >> 16)),    s.x, s.y), 0.f);
        *(float4*)(out + e) = o0;
        *(float4*)(out + e + 4) = o1;
    }
}

extern "C" void kernel_launch(void* const* d_in, const int* in_sizes, int n_in,
                              void* d_out, int out_size, void* d_ws, size_t ws_size,
                              hipStream_t stream)
{
    const float* x    = (const float*)d_in[0];
    const float* bw   = (const float*)d_in[1];
    const float* bb   = (const float*)d_in[2];
    const float* bs   = (const float*)d_in[3];
    const float* ww0  = (const float*)d_in[4];
    const float* ww1  = (const float*)d_in[5];
    const float* ww2  = (const float*)d_in[6];
    const float* ws0  = (const float*)d_in[7];
    const float* ws1  = (const float*)d_in[8];
    const float* ws2  = (const float*)d_in[9];
    const float* gamma = (const float*)d_in[10];
    const float* beta  = (const float*)d_in[11];

    char* w = (char*)d_ws;
    // ybf [0,134.2M) overlaps ONLY cur1 [0,67.1M) (dead after K2, before K6).
    unsigned short* ybf = (unsigned short*)(w);                    // 134.2 MB
    float*          cur1 = (float*)(w);                            // 67.1 MB (alias)
    unsigned short* t1   = (unsigned short*)(w + 134217728);       // 33.6 MB bf16
    float*          cur2 = (float*)(w + 167772160);                // 16.8 MB
    unsigned short* t2   = (unsigned short*)(w + 184549376);       // 8.4 MB bf16
    float2*         partials = (float2*)(w + 192937984);           // 128 KB
    float2*         ab       = (float2*)(w + 193069056);

    // K1: x -> cur1 (LL only)
    ll_kernel<<<dim3(NB * NC * 128 * 64 / 256), 256, 0, stream>>>(x, cur1);
    // K2: level 1 (bf16 bands + fp32 LL)
    dwt_conv_kernel<128><<<dim3(4, NC, NB), 256, 0, stream>>>(cur1, ww1, ws1, t1, cur2);
    // K3: level 2 (bf16 bands)
    dwt_conv_kernel<64><<<dim3(1, NC, NB), 256, 0, stream>>>(cur2, ww2, ws2, t2, nullptr);
    // K6: base conv + level-0 dwt/conv/idwt + inline 2-level recon -> ybf + partials
    final_fuse_kernel<<<dim3(16, NC, NB), 256, 0, stream>>>(x, t1, t2, bw, bb, bs, ww0, ws0, ybf, partials);
    // K7: BN stats
    stats_kernel<<<dim3(64), 256, 0, stream>>>(partials, gamma, beta, ab);
    // K8: normalize + relu -> d_out (fp32)
    norm_out_kernel<<<dim3(2048), 256, 0, stream>>>(ybf, ab, (float*)d_out);
}

// Round 8
// 347.009 us; speedup vs baseline: 1.1849x; 1.1849x over previous
//
#include <hip/hip_runtime.h>
#include <hip/hip_bf16.h>

#define NB 16
#define NC 64

static __device__ __forceinline__ unsigned short f2bfr(float f) {
    union { float f; unsigned u; } cv; cv.f = f;
    unsigned r = cv.u + 0x7fffu + ((cv.u >> 16) & 1u);
    return (unsigned short)(r >> 16);
}
static __device__ __forceinline__ float bfr2f(unsigned short h) {
    union { unsigned u; float f; } cv; cv.u = ((unsigned)h) << 16;
    return cv.f;
}
static __device__ __forceinline__ unsigned pack2bf(float lo, float hi) {
    return ((unsigned)f2bfr(lo)) | (((unsigned)f2bfr(hi)) << 16);
}

// ---------------------------------------------------------------------------
// Shift-addressed float4 staging of a 68-row x 72-col halo tile, stride 76.
// ---------------------------------------------------------------------------
template <int H>
static __device__ __forceinline__ void stage_tile(
    const float* __restrict__ src, size_t ibase, int sTop, int sLeft,
    float (*sIn)[76], int tid)
{
#pragma unroll
    for (int i = 0; i < 5; ++i) {
        int idx = i * 256 + tid;
        if (idx < 68 * 16) {
            int r = idx >> 4, c4 = (idx & 15) << 2;
            int gy = sTop + r, gx = sLeft + c4;
            float4 v = make_float4(0.f, 0.f, 0.f, 0.f);
            if ((unsigned)gy < (unsigned)H && (unsigned)gx < (unsigned)H)
                v = *(const float4*)(src + ibase + (size_t)gy * H + gx);
            *(float4*)(&sIn[r][c4]) = v;
        }
    }
    if (tid < 136) {
        int r = tid >> 1, c4 = 64 + ((tid & 1) << 2);
        int gy = sTop + r, gx = sLeft + c4;
        float4 v = make_float4(0.f, 0.f, 0.f, 0.f);
        if ((unsigned)gy < (unsigned)H && (unsigned)gx < (unsigned)H)
            v = *(const float4*)(src + ibase + (size_t)gy * H + gx);
        *(float4*)(&sIn[r][c4]) = v;
    }
}

// ---------------------------------------------------------------------------
// K1: LL band of Haar DWT of x: (B,C,256,256) -> (B,C,128,128). Pure stream.
// ---------------------------------------------------------------------------
__global__ __launch_bounds__(256) void ll_kernel(
    const float* __restrict__ in, float* __restrict__ ll)
{
    int t = blockIdx.x * 256 + threadIdx.x;
    int jp  = t & 63;
    int i   = (t >> 6) & 127;
    int img = t >> 13;
    size_t ib = (size_t)img * 65536;
    float4 a = *(const float4*)(in + ib + (size_t)(2 * i) * 256 + 4 * jp);
    float4 b = *(const float4*)(in + ib + (size_t)(2 * i + 1) * 256 + 4 * jp);
    float2 o;
    o.x = 0.5f * (a.x + a.y + b.x + b.y);
    o.y = 0.5f * (a.z + a.w + b.z + b.w);
    *(float2*)(ll + (size_t)img * 16384 + (size_t)i * 128 + 2 * jp) = o;
}

// ---------------------------------------------------------------------------
// K2/K3: fused Haar DWT + depthwise 3x3 conv + scale. 2x2 outputs/thread,
// shared register DWT. in fp32 -> t bf16, curn fp32 = pre-conv LL.
// ---------------------------------------------------------------------------
template <int H>
__global__ __launch_bounds__(256) void dwt_conv_kernel(
    const float* __restrict__ in, const float* __restrict__ ww,
    const float* __restrict__ wsc, unsigned short* __restrict__ t_out,
    float* __restrict__ curn)
{
    constexpr int H2 = H / 2;
    constexpr int TX = H2 / 32;
    const int tile = blockIdx.x;
    const int c = blockIdx.y, b = blockIdx.z;
    const int ty = tile / TX, tx = tile % TX;
    const int oy0 = ty * 32, ox0 = tx * 32;
    const int tid = threadIdx.x;
    const int qi = 2 * (tid >> 4), qj = 2 * (tid & 15);

    __shared__ float sIn[68][76];

    float w[4][9], sc[4];
#pragma unroll
    for (int k = 0; k < 4; ++k) {
#pragma unroll
        for (int i = 0; i < 9; ++i) w[k][i] = ww[(c * 4 + k) * 9 + i];
        sc[k] = 0.5f * wsc[c * 4 + k];
    }

    const size_t ibase = (size_t)(b * NC + c) * H * H;
    stage_tile<H>(in, ibase, 2 * oy0 - 2, 2 * ox0 - 4, sIn, tid);
    __syncthreads();

    float kk[4][4];
#pragma unroll
    for (int i = 0; i < 4; ++i)
#pragma unroll
        for (int j = 0; j < 4; ++j) kk[i][j] = 0.f;
    float llc[4];

    const int pr0 = 2 * qi, pc0 = 2 * qj + 2;
#pragma unroll
    for (int rp = 0; rp < 4; ++rp) {
        float xa[8], xb[8];
#pragma unroll
        for (int n = 0; n < 4; ++n) {
            float2 va = *(const float2*)&sIn[pr0 + 2 * rp][pc0 + 2 * n];
            float2 vb = *(const float2*)&sIn[pr0 + 2 * rp + 1][pc0 + 2 * n];
            xa[2 * n] = va.x; xa[2 * n + 1] = va.y;
            xb[2 * n] = vb.x; xb[2 * n + 1] = vb.y;
        }
        float D0[4], D1[4], D2[4], D3[4];
#pragma unroll
        for (int n = 0; n < 4; ++n) {
            float a = xa[2 * n], e = xa[2 * n + 1];
            float f = xb[2 * n], g = xb[2 * n + 1];
            float s0 = a + e, s1 = f + g, d0 = a - e, d1 = f - g;
            D0[n] = s0 + s1; D1[n] = s0 - s1;
            D2[n] = d0 + d1; D3[n] = d0 - d1;
        }
#pragma unroll
        for (int mi = 0; mi < 2; ++mi) {
            const int r = rp - mi;
            if (r >= 0 && r <= 2) {
#pragma unroll
                for (int mj = 0; mj < 2; ++mj) {
                    const int m = 2 * mi + mj;
#pragma unroll
                    for (int s = 0; s < 3; ++s) {
                        kk[0][m] = fmaf(w[0][3 * r + s], D0[mj + s], kk[0][m]);
                        kk[1][m] = fmaf(w[1][3 * r + s], D1[mj + s], kk[1][m]);
                        kk[2][m] = fmaf(w[2][3 * r + s], D2[mj + s], kk[2][m]);
                        kk[3][m] = fmaf(w[3][3 * r + s], D3[mj + s], kk[3][m]);
                    }
                }
                if (r == 1) {
                    llc[2 * mi + 0] = 0.5f * D0[1];
                    llc[2 * mi + 1] = 0.5f * D0[2];
                }
            }
        }
    }

    const size_t tbase = (size_t)(b * NC + c) * 4 * H2 * H2;
    const size_t o00 = (size_t)(oy0 + qi) * H2 + (ox0 + qj);
#pragma unroll
    for (int band = 0; band < 4; ++band) {
        size_t bo = tbase + (size_t)band * H2 * H2 + o00;
#pragma unroll
        for (int mi = 0; mi < 2; ++mi)
            *(unsigned*)(t_out + bo + (size_t)mi * H2) =
                pack2bf(kk[band][2 * mi] * sc[band], kk[band][2 * mi + 1] * sc[band]);
    }
    if (curn) {
        const size_t cbase = (size_t)(b * NC + c) * H2 * H2 + o00;
        *(float2*)(curn + cbase)      = make_float2(llc[0], llc[1]);
        *(float2*)(curn + cbase + H2) = make_float2(llc[2], llc[3]);
    }
}

// ---------------------------------------------------------------------------
// K45: fused 2-level reconstruction, all bf16: idwt(t2) -> idwt(t1) -> nxt1.
// ---------------------------------------------------------------------------
__global__ __launch_bounds__(256) void idwt_fuse_kernel(
    const unsigned short* __restrict__ t1, const unsigned short* __restrict__ t2,
    unsigned short* __restrict__ nxt1)
{
    int idx = blockIdx.x * 256 + threadIdx.x;   // NB*NC*4096
    int j = idx & 63, i = (idx >> 6) & 63, img = idx >> 12;
    size_t t2b = (size_t)img * 4096 + (size_t)(i >> 1) * 32 + (j >> 1);
    float m0 = bfr2f(t2[t2b]);
    float m1 = bfr2f(t2[t2b + 1024]);
    float m2 = bfr2f(t2[t2b + 2048]);
    float m3 = bfr2f(t2[t2b + 3072]);
    float a1 = (i & 1) ? -m1 : m1;
    float a2 = (j & 1) ? -m2 : m2;
    float a3 = ((i ^ j) & 1) ? -m3 : m3;
    float nxt2v = 0.5f * (m0 + a1 + a2 + a3);
    size_t t1b = (size_t)img * 16384 + (size_t)i * 64 + j;
    float k0 = bfr2f(t1[t1b]) + nxt2v;
    float k1 = bfr2f(t1[t1b + 4096]);
    float k2 = bfr2f(t1[t1b + 8192]);
    float k3 = bfr2f(t1[t1b + 12288]);
    size_t ob = (size_t)img * 16384 + (size_t)(2 * i) * 128 + 2 * j;
    *(unsigned*)(nxt1 + ob)       = pack2bf(0.5f * (k0 + k1 + k2 + k3),
                                            0.5f * (k0 + k1 - k2 - k3));
    *(unsigned*)(nxt1 + ob + 128) = pack2bf(0.5f * (k0 - k1 + k2 - k3),
                                            0.5f * (k0 - k1 - k2 + k3));
}

// ---------------------------------------------------------------------------
// K6: final fuse (round-6 proven structure: 1 quad/iter, low VGPR).
// Register DWT -> band convs -> IDWT (nxt1 bf16) + base conv -> y bf16 +
// deterministic BN partials. 64x64 pixel tile, 256 threads.
// ---------------------------------------------------------------------------
__global__ __launch_bounds__(256) void final_fuse_kernel(
    const float* __restrict__ x, const unsigned short* __restrict__ nxt1,
    const float* __restrict__ bw, const float* __restrict__ bb,
    const float* __restrict__ bs, const float* __restrict__ ww0,
    const float* __restrict__ ws0,
    unsigned short* __restrict__ ybf, float2* __restrict__ partials)
{
    const int tile = blockIdx.x, c = blockIdx.y, b = blockIdx.z;
    const int ty = tile >> 2, tx = tile & 3;
    const int oy0 = ty * 64, ox0 = tx * 64;
    const int hy0 = ty * 32, hx0 = tx * 32;
    const int tid = threadIdx.x;

    __shared__ float sIn[68][76];
    __shared__ float rS[256], rQ[256];

    float w[4][9], sc[4], wb[9];
#pragma unroll
    for (int k = 0; k < 4; ++k) {
#pragma unroll
        for (int i = 0; i < 9; ++i) w[k][i] = ww0[(c * 4 + k) * 9 + i];
        sc[k] = 0.25f * ws0[c * 4 + k];   // DWT 0.5 x IDWT 0.5
    }
#pragma unroll
    for (int i = 0; i < 9; ++i) wb[i] = bw[c * 9 + i];
    const float scale = bs[c];
    const float bsc = bb[c] * scale;

    const size_t xb = (size_t)(b * NC + c) * 65536;
    stage_tile<256>(x, xb, oy0 - 2, ox0 - 4, sIn, tid);
    __syncthreads();

    const size_t n1b = (size_t)(b * NC + c) * 16384;
    const int qj = tid & 31;
    const int qi0 = tid >> 5;
    float lsum = 0.f, lss = 0.f;
#pragma unroll
    for (int it = 0; it < 4; ++it) {
        int qi = qi0 + 8 * it;
        float P[6][6];
#pragma unroll
        for (int r = 0; r < 6; ++r) {
            const float2* rp = (const float2*)&sIn[2 * qi + r][2 * qj + 2];
            float2 p0 = rp[0], p1 = rp[1], p2 = rp[2];
            P[r][0] = p0.x; P[r][1] = p0.y; P[r][2] = p1.x;
            P[r][3] = p1.y; P[r][4] = p2.x; P[r][5] = p2.y;
        }
        float kk0 = 0.f, kk1 = 0.f, kk2 = 0.f, kk3 = 0.f;
#pragma unroll
        for (int r = 0; r < 3; ++r)
#pragma unroll
            for (int s = 0; s < 3; ++s) {
                float a = P[2*r][2*s],   e = P[2*r][2*s+1];
                float f = P[2*r+1][2*s], g = P[2*r+1][2*s+1];
                float s0 = a + e, s1 = f + g, d0 = a - e, d1 = f - g;
                kk0 += w[0][3*r+s] * (s0 + s1);
                kk1 += w[1][3*r+s] * (s0 - s1);
                kk2 += w[2][3*r+s] * (d0 + d1);
                kk3 += w[3][3*r+s] * (d0 - d1);
            }
        kk0 = kk0 * sc[0] + 0.5f * bfr2f(nxt1[n1b + (size_t)(hy0 + qi) * 128 + (hx0 + qj)]);
        kk1 *= sc[1];
        kk2 *= sc[2];
        kk3 *= sc[3];
        float vv[2][2];
        vv[0][0] = kk0 + kk1 + kk2 + kk3;
        vv[0][1] = kk0 + kk1 - kk2 - kk3;
        vv[1][0] = kk0 - kk1 + kk2 - kk3;
        vv[1][1] = kk0 - kk1 - kk2 + kk3;
        int yl = 2 * qi, xl = 2 * qj;
#pragma unroll
        for (int p = 0; p < 2; ++p) {
            unsigned pack = 0;
#pragma unroll
            for (int q = 0; q < 2; ++q) {
                float acc = 0.f;
#pragma unroll
                for (int r = 0; r < 3; ++r)
#pragma unroll
                    for (int s = 0; s < 3; ++s)
                        acc += P[p + r + 1][q + s + 1] * wb[3 * r + s];
                float val = fmaf(acc, scale, bsc) + vv[p][q];
                lsum += val;
                lss = fmaf(val, val, lss);
                pack |= ((unsigned)f2bfr(val)) << (16 * q);
            }
            *(unsigned*)(ybf + xb + (size_t)(oy0 + yl + p) * 256 + (ox0 + xl)) = pack;
        }
    }
    rS[tid] = lsum;
    rQ[tid] = lss;
    __syncthreads();
    for (int off = 128; off > 0; off >>= 1) {
        if (tid < off) { rS[tid] += rS[tid + off]; rQ[tid] += rQ[tid + off]; }
        __syncthreads();
    }
    if (tid == 0)
        partials[c * 256 + b * 16 + tile] = make_float2(rS[0], rQ[0]);
}

// ---------------------------------------------------------------------------
// K7: per-channel BN stats -> (a,b). 64 blocks x 256 threads.
// ---------------------------------------------------------------------------
__global__ __launch_bounds__(256) void stats_kernel(
    const float2* __restrict__ partials, const float* __restrict__ gamma,
    const float* __restrict__ beta, float2* __restrict__ ab)
{
    const int c = blockIdx.x;
    const int tid = threadIdx.x;
    __shared__ float s1[256], s2[256];
    float2 p = partials[c * 256 + tid];
    s1[tid] = p.x;
    s2[tid] = p.y;
    __syncthreads();
    for (int off = 128; off > 0; off >>= 1) {
        if (tid < off) { s1[tid] += s1[tid + off]; s2[tid] += s2[tid + off]; }
        __syncthreads();
    }
    if (tid == 0) {
        const float N = (float)NB * 65536.0f;
        float mean = s1[0] / N;
        float var = s2[0] / N - mean * mean;
        float inv = rsqrtf(var + 1e-5f);
        float a = gamma[c] * inv;
        ab[c] = make_float2(a, beta[c] - mean * a);
    }
}

// ---------------------------------------------------------------------------
// K8: normalize + ReLU: bf16 y-staging -> fp32 d_out. 8 elems per iter.
// ---------------------------------------------------------------------------
__global__ __launch_bounds__(256) void norm_out_kernel(
    const unsigned short* __restrict__ ybf, const float2* __restrict__ ab,
    float* __restrict__ out)
{
    const long total8 = (long)NB * NC * 65536 / 8;
    const long stride = (long)gridDim.x * 256;
    for (long i = blockIdx.x * 256L + threadIdx.x; i < total8; i += stride) {
        long e = i * 8;
        int c = (int)((e >> 16) & (NC - 1));
        float2 s = ab[c];
        uint4 v = *(const uint4*)(ybf + e);
        float4 o0, o1;
        o0.x = fmaxf(fmaf(bfr2f((unsigned short)(v.x & 0xffff)), s.x, s.y), 0.f);
        o0.y = fmaxf(fmaf(bfr2f((unsigned short)(v.x >> 16)),    s.x, s.y), 0.f);
        o0.z = fmaxf(fmaf(bfr2f((unsigned short)(v.y & 0xffff)), s.x, s.y), 0.f);
        o0.w = fmaxf(fmaf(bfr2f((unsigned short)(v.y >> 16)),    s.x, s.y), 0.f);
        o1.x = fmaxf(fmaf(bfr2f((unsigned short)(v.z & 0xffff)), s.x, s.y), 0.f);
        o1.y = fmaxf(fmaf(bfr2f((unsigned short)(v.z >> 16)),    s.x, s.y), 0.f);
        o1.z = fmaxf(fmaf(bfr2f((unsigned short)(v.w & 0xffff)), s.x, s.y), 0.f);
        o1.w = fmaxf(fmaf(bfr2f((unsigned short)(v.w >> 16)),    s.x, s.y), 0.f);
        *(float4*)(out + e) = o0;
        *(float4*)(out + e + 4) = o1;
    }
}

extern "C" void kernel_launch(void* const* d_in, const int* in_sizes, int n_in,
                              void* d_out, int out_size, void* d_ws, size_t ws_size,
                              hipStream_t stream)
{
    const float* x    = (const float*)d_in[0];
    const float* bw   = (const float*)d_in[1];
    const float* bb   = (const float*)d_in[2];
    const float* bs   = (const float*)d_in[3];
    const float* ww0  = (const float*)d_in[4];
    const float* ww1  = (const float*)d_in[5];
    const float* ww2  = (const float*)d_in[6];
    const float* ws0  = (const float*)d_in[7];
    const float* ws1  = (const float*)d_in[8];
    const float* ws2  = (const float*)d_in[9];
    const float* gamma = (const float*)d_in[10];
    const float* beta  = (const float*)d_in[11];

    char* w = (char*)d_ws;
    // ybf [0,134.2M) aliases cur1 [0,67.1M) (cur1 dead after K2, ybf born K6).
    unsigned short* ybf  = (unsigned short*)(w);                   // 134.2 MB
    float*          cur1 = (float*)(w);                            // 67.1 MB (alias)
    unsigned short* t1   = (unsigned short*)(w + 134217728);       // 33.6 MB bf16
    float*          cur2 = (float*)(w + 167772160);                // 16.8 MB fp32
    unsigned short* t2   = (unsigned short*)(w + 184549376);       // 8.4 MB bf16
    unsigned short* nxt1 = (unsigned short*)(w + 192937984);       // 33.6 MB bf16
    float2*         partials = (float2*)(w + 226492416);           // 128 KB
    float2*         ab       = (float2*)(w + 226623488);

    // K1: x -> cur1 (LL only)
    ll_kernel<<<dim3(NB * NC * 128 * 64 / 256), 256, 0, stream>>>(x, cur1);
    // K2: level 1 (bf16 bands + fp32 LL)
    dwt_conv_kernel<128><<<dim3(4, NC, NB), 256, 0, stream>>>(cur1, ww1, ws1, t1, cur2);
    // K3: level 2 (bf16 bands)
    dwt_conv_kernel<64><<<dim3(1, NC, NB), 256, 0, stream>>>(cur2, ww2, ws2, t2, nullptr);
    // K45: fused recon level2+1 -> nxt1 (all bf16)
    idwt_fuse_kernel<<<dim3(NB * NC * 4096 / 256), 256, 0, stream>>>(t1, t2, nxt1);
    // K6: base conv + level-0 dwt/conv/idwt -> ybf (bf16) + partials
    final_fuse_kernel<<<dim3(16, NC, NB), 256, 0, stream>>>(x, nxt1, bw, bb, bs, ww0, ws0, ybf, partials);
    // K7: BN stats
    stats_kernel<<<dim3(64), 256, 0, stream>>>(partials, gamma, beta, ab);
    // K8: normalize + relu -> d_out (fp32)
    norm_out_kernel<<<dim3(2048), 256, 0, stream>>>(ybf, ab, (float*)d_out);
}

// Round 9
// 316.681 us; speedup vs baseline: 1.2984x; 1.0958x over previous
//
#include <hip/hip_runtime.h>
#include <hip/hip_bf16.h>

#define NB 16
#define NC 64

static __device__ __forceinline__ float bfr2f(unsigned short h) {
    union { unsigned u; float f; } cv; cv.u = ((unsigned)h) << 16;
    return cv.f;
}
// 1-instruction packed fp32->bf16 (RNE) [gfx950 v_cvt_pk_bf16_f32]
static __device__ __forceinline__ unsigned cvt_pk_bf16(float lo, float hi) {
    unsigned r;
    asm("v_cvt_pk_bf16_f32 %0, %1, %2" : "=v"(r) : "v"(lo), "v"(hi));
    return r;
}

// ---------------------------------------------------------------------------
// Shift-addressed float4 staging of a 68-row x 72-col halo tile, stride 76.
// ---------------------------------------------------------------------------
template <int H>
static __device__ __forceinline__ void stage_tile(
    const float* __restrict__ src, size_t ibase, int sTop, int sLeft,
    float (*sIn)[76], int tid)
{
#pragma unroll
    for (int i = 0; i < 5; ++i) {
        int idx = i * 256 + tid;
        if (idx < 68 * 16) {
            int r = idx >> 4, c4 = (idx & 15) << 2;
            int gy = sTop + r, gx = sLeft + c4;
            float4 v = make_float4(0.f, 0.f, 0.f, 0.f);
            if ((unsigned)gy < (unsigned)H && (unsigned)gx < (unsigned)H)
                v = *(const float4*)(src + ibase + (size_t)gy * H + gx);
            *(float4*)(&sIn[r][c4]) = v;
        }
    }
    if (tid < 136) {
        int r = tid >> 1, c4 = 64 + ((tid & 1) << 2);
        int gy = sTop + r, gx = sLeft + c4;
        float4 v = make_float4(0.f, 0.f, 0.f, 0.f);
        if ((unsigned)gy < (unsigned)H && (unsigned)gx < (unsigned)H)
            v = *(const float4*)(src + ibase + (size_t)gy * H + gx);
        *(float4*)(&sIn[r][c4]) = v;
    }
}

// ---------------------------------------------------------------------------
// Shared phase-2 body: level DWT + depthwise conv on a staged 68x72 LL tile.
// 2x2 outputs/thread. Writes t bf16 (+ optional fp32 next-level LL).
// ---------------------------------------------------------------------------
template <int H2>
static __device__ __forceinline__ void dwt_conv_body(
    const float (*sIn)[76], const float* __restrict__ ww,
    const float* __restrict__ wsc, unsigned short* __restrict__ t_out,
    float* __restrict__ curn, int c, int b, int oy0, int ox0, int tid)
{
    const int qi = 2 * (tid >> 4), qj = 2 * (tid & 15);

    float w[4][9], sc[4];
#pragma unroll
    for (int k = 0; k < 4; ++k) {
#pragma unroll
        for (int i = 0; i < 9; ++i) w[k][i] = ww[(c * 4 + k) * 9 + i];
        sc[k] = 0.5f * wsc[c * 4 + k];
    }

    float kk[4][4];
#pragma unroll
    for (int i = 0; i < 4; ++i)
#pragma unroll
        for (int j = 0; j < 4; ++j) kk[i][j] = 0.f;
    float llc[4];

    const int pr0 = 2 * qi, pc0 = 2 * qj + 2;
#pragma unroll
    for (int rp = 0; rp < 4; ++rp) {
        float xa[8], xb[8];
#pragma unroll
        for (int n = 0; n < 4; ++n) {
            float2 va = *(const float2*)&sIn[pr0 + 2 * rp][pc0 + 2 * n];
            float2 vb = *(const float2*)&sIn[pr0 + 2 * rp + 1][pc0 + 2 * n];
            xa[2 * n] = va.x; xa[2 * n + 1] = va.y;
            xb[2 * n] = vb.x; xb[2 * n + 1] = vb.y;
        }
        float D0[4], D1[4], D2[4], D3[4];
#pragma unroll
        for (int n = 0; n < 4; ++n) {
            float a = xa[2 * n], e = xa[2 * n + 1];
            float f = xb[2 * n], g = xb[2 * n + 1];
            float s0 = a + e, s1 = f + g, d0 = a - e, d1 = f - g;
            D0[n] = s0 + s1; D1[n] = s0 - s1;
            D2[n] = d0 + d1; D3[n] = d0 - d1;
        }
#pragma unroll
        for (int mi = 0; mi < 2; ++mi) {
            const int r = rp - mi;
            if (r >= 0 && r <= 2) {
#pragma unroll
                for (int mj = 0; mj < 2; ++mj) {
                    const int m = 2 * mi + mj;
#pragma unroll
                    for (int s = 0; s < 3; ++s) {
                        kk[0][m] = fmaf(w[0][3 * r + s], D0[mj + s], kk[0][m]);
                        kk[1][m] = fmaf(w[1][3 * r + s], D1[mj + s], kk[1][m]);
                        kk[2][m] = fmaf(w[2][3 * r + s], D2[mj + s], kk[2][m]);
                        kk[3][m] = fmaf(w[3][3 * r + s], D3[mj + s], kk[3][m]);
                    }
                }
                if (r == 1) {
                    llc[2 * mi + 0] = 0.5f * D0[1];
                    llc[2 * mi + 1] = 0.5f * D0[2];
                }
            }
        }
    }

    const size_t tbase = (size_t)(b * NC + c) * 4 * H2 * H2;
    const size_t o00 = (size_t)(oy0 + qi) * H2 + (ox0 + qj);
#pragma unroll
    for (int band = 0; band < 4; ++band) {
        size_t bo = tbase + (size_t)band * H2 * H2 + o00;
#pragma unroll
        for (int mi = 0; mi < 2; ++mi)
            *(unsigned*)(t_out + bo + (size_t)mi * H2) =
                cvt_pk_bf16(kk[band][2 * mi] * sc[band], kk[band][2 * mi + 1] * sc[band]);
    }
    if (curn) {
        const size_t cbase = (size_t)(b * NC + c) * H2 * H2 + o00;
        *(float2*)(curn + cbase)      = make_float2(llc[0], llc[1]);
        *(float2*)(curn + cbase + H2) = make_float2(llc[2], llc[3]);
    }
}

// ---------------------------------------------------------------------------
// K2': level-1 DWT+conv with the LL halo computed DIRECTLY from x (fuses the
// old ll_kernel). Phase 1: 68x68 LL from x float4 pairs -> LDS. Phase 2: body.
// ---------------------------------------------------------------------------
__global__ __launch_bounds__(256) void dwt_conv_from_x_kernel(
    const float* __restrict__ x, const float* __restrict__ ww,
    const float* __restrict__ wsc, unsigned short* __restrict__ t_out,
    float* __restrict__ curn)
{
    const int tile = blockIdx.x;            // 4 tiles (2x2) of 32x32 @64-res
    const int c = blockIdx.y, b = blockIdx.z;
    const int ty = tile >> 1, tx = tile & 1;
    const int oy0 = ty * 32, ox0 = tx * 32;
    const int tid = threadIdx.x;

    __shared__ float sLL[68][76];

    const size_t xbase = (size_t)(b * NC + c) * 65536;
    const int gy0 = 4 * oy0 - 4;    // x row of LL rel row 0
    const int gx0 = 4 * ox0 - 8;    // x col of LL rel col 0
    for (int u = tid; u < 68 * 36; u += 256) {
        int r = u / 36, cp = u - r * 36;       // LL row, col-pair index
        int gy = gy0 + 2 * r, gx = gx0 + 4 * cp;
        float4 va = make_float4(0.f, 0.f, 0.f, 0.f);
        float4 vb = va;
        if ((unsigned)gy < 256u && (unsigned)gx < 256u) {
            va = *(const float4*)(x + xbase + (size_t)gy * 256 + gx);
            vb = *(const float4*)(x + xbase + (size_t)(gy + 1) * 256 + gx);
        }
        *(float2*)(&sLL[r][2 * cp]) =
            make_float2(0.5f * (va.x + va.y + vb.x + vb.y),
                        0.5f * (va.z + va.w + vb.z + vb.w));
    }
    __syncthreads();

    dwt_conv_body<64>(sLL, ww, wsc, t_out, curn, c, b, oy0, ox0, tid);
}

// ---------------------------------------------------------------------------
// K3: level-2 DWT+conv reading staged fp32 cur2.
// ---------------------------------------------------------------------------
__global__ __launch_bounds__(256) void dwt_conv_kernel64(
    const float* __restrict__ in, const float* __restrict__ ww,
    const float* __restrict__ wsc, unsigned short* __restrict__ t_out)
{
    const int c = blockIdx.y, b = blockIdx.z;
    const int tid = threadIdx.x;
    __shared__ float sIn[68][76];
    const size_t ibase = (size_t)(b * NC + c) * 64 * 64;
    stage_tile<64>(in, ibase, -2, -4, sIn, tid);
    __syncthreads();
    dwt_conv_body<32>(sIn, ww, wsc, t_out, nullptr, c, b, 0, 0, tid);
}

// ---------------------------------------------------------------------------
// K45: fused 2-level reconstruction, all bf16: idwt(t2) -> idwt(t1) -> nxt1.
// ---------------------------------------------------------------------------
__global__ __launch_bounds__(256) void idwt_fuse_kernel(
    const unsigned short* __restrict__ t1, const unsigned short* __restrict__ t2,
    unsigned short* __restrict__ nxt1)
{
    int idx = blockIdx.x * 256 + threadIdx.x;   // NB*NC*4096
    int j = idx & 63, i = (idx >> 6) & 63, img = idx >> 12;
    size_t t2b = (size_t)img * 4096 + (size_t)(i >> 1) * 32 + (j >> 1);
    float m0 = bfr2f(t2[t2b]);
    float m1 = bfr2f(t2[t2b + 1024]);
    float m2 = bfr2f(t2[t2b + 2048]);
    float m3 = bfr2f(t2[t2b + 3072]);
    float a1 = (i & 1) ? -m1 : m1;
    float a2 = (j & 1) ? -m2 : m2;
    float a3 = ((i ^ j) & 1) ? -m3 : m3;
    float nxt2v = 0.5f * (m0 + a1 + a2 + a3);
    size_t t1b = (size_t)img * 16384 + (size_t)i * 64 + j;
    float k0 = bfr2f(t1[t1b]) + nxt2v;
    float k1 = bfr2f(t1[t1b + 4096]);
    float k2 = bfr2f(t1[t1b + 8192]);
    float k3 = bfr2f(t1[t1b + 12288]);
    size_t ob = (size_t)img * 16384 + (size_t)(2 * i) * 128 + 2 * j;
    *(unsigned*)(nxt1 + ob)       = cvt_pk_bf16(0.5f * (k0 + k1 + k2 + k3),
                                                0.5f * (k0 + k1 - k2 - k3));
    *(unsigned*)(nxt1 + ob + 128) = cvt_pk_bf16(0.5f * (k0 - k1 + k2 - k3),
                                                0.5f * (k0 - k1 - k2 + k3));
}

// ---------------------------------------------------------------------------
// K6: final fuse, vertical quad-pair version. Each thread: 2 passes x
// (2 stacked quads = 4x2 px) from one 8-row x 6-col patch. Register DWT ->
// band convs -> IDWT (nxt1 bf16) + base conv -> y bf16 + BN partials.
// ---------------------------------------------------------------------------
__global__ __launch_bounds__(256) void final_fuse_kernel(
    const float* __restrict__ x, const unsigned short* __restrict__ nxt1,
    const float* __restrict__ bw, const float* __restrict__ bb,
    const float* __restrict__ bs, const float* __restrict__ ww0,
    const float* __restrict__ ws0,
    unsigned short* __restrict__ ybf, float2* __restrict__ partials)
{
    const int tile = blockIdx.x, c = blockIdx.y, b = blockIdx.z;
    const int ty = tile >> 2, tx = tile & 3;
    const int oy0 = ty * 64, ox0 = tx * 64;
    const int hy0 = ty * 32, hx0 = tx * 32;
    const int tid = threadIdx.x;
    const int qj = tid & 31;          // quad column 0..31
    const int pr = tid >> 5;          // pair-row 0..7 (of 16, 2 passes)

    __shared__ float sIn[68][76];
    __shared__ float2 sW4[4];

    float w[4][9], sc[4], wb[9];
#pragma unroll
    for (int k = 0; k < 4; ++k) {
#pragma unroll
        for (int i = 0; i < 9; ++i) w[k][i] = ww0[(c * 4 + k) * 9 + i];
        sc[k] = 0.25f * ws0[c * 4 + k];   // DWT 0.5 x IDWT 0.5
    }
#pragma unroll
    for (int i = 0; i < 9; ++i) wb[i] = bw[c * 9 + i];
    const float scale = bs[c];
    const float bsc = bb[c] * scale;

    const size_t xb = (size_t)(b * NC + c) * 65536;
    stage_tile<256>(x, xb, oy0 - 2, ox0 - 4, sIn, tid);
    __syncthreads();

    const size_t n1b = (size_t)(b * NC + c) * 16384;
    float lsum = 0.f, lss = 0.f;

#pragma unroll
    for (int pass = 0; pass < 2; ++pass) {
        const int pair = pr + 8 * pass;       // 0..15
        const int h0 = 2 * pair;              // upper quad half-res row
        const int prow0 = 4 * pair;           // patch base row in sIn
        const int pc0 = 2 * qj + 2;

        float kkA[4], kkB[4];
#pragma unroll
        for (int k = 0; k < 4; ++k) { kkA[k] = 0.f; kkB[k] = 0.f; }
        float acc[4][2];
#pragma unroll
        for (int p = 0; p < 4; ++p) { acc[p][0] = 0.f; acc[p][1] = 0.f; }

#pragma unroll
        for (int rp = 0; rp < 4; ++rp) {
            float xa[6], xv[6];
#pragma unroll
            for (int n = 0; n < 3; ++n) {
                float2 va = *(const float2*)&sIn[prow0 + 2 * rp][pc0 + 2 * n];
                float2 vb = *(const float2*)&sIn[prow0 + 2 * rp + 1][pc0 + 2 * n];
                xa[2 * n] = va.x; xa[2 * n + 1] = va.y;
                xv[2 * n] = vb.x; xv[2 * n + 1] = vb.y;
            }
            float D0[3], D1[3], D2[3], D3[3];
#pragma unroll
            for (int n = 0; n < 3; ++n) {
                float a = xa[2 * n], e = xa[2 * n + 1];
                float f = xv[2 * n], g = xv[2 * n + 1];
                float s0 = a + e, s1 = f + g, d0 = a - e, d1 = f - g;
                D0[n] = s0 + s1; D1[n] = s0 - s1;
                D2[n] = d0 + d1; D3[n] = d0 - d1;
            }
            if (rp <= 2) {
#pragma unroll
                for (int s = 0; s < 3; ++s) {
                    kkA[0] = fmaf(w[0][3 * rp + s], D0[s], kkA[0]);
                    kkA[1] = fmaf(w[1][3 * rp + s], D1[s], kkA[1]);
                    kkA[2] = fmaf(w[2][3 * rp + s], D2[s], kkA[2]);
                    kkA[3] = fmaf(w[3][3 * rp + s], D3[s], kkA[3]);
                }
            }
            if (rp >= 1) {
                const int r = rp - 1;
#pragma unroll
                for (int s = 0; s < 3; ++s) {
                    kkB[0] = fmaf(w[0][3 * r + s], D0[s], kkB[0]);
                    kkB[1] = fmaf(w[1][3 * r + s], D1[s], kkB[1]);
                    kkB[2] = fmaf(w[2][3 * r + s], D2[s], kkB[2]);
                    kkB[3] = fmaf(w[3][3 * r + s], D3[s], kkB[3]);
                }
            }
            // base conv: xa = patch row 2rp, xv = row 2rp+1
#pragma unroll
            for (int py = 0; py < 4; ++py) {
                const int rra = 2 * rp - py - 1;
                if (rra >= 0 && rra <= 2) {
#pragma unroll
                    for (int u = 0; u < 2; ++u)
                        acc[py][u] = fmaf(xa[u + 1], wb[3 * rra],
                                     fmaf(xa[u + 2], wb[3 * rra + 1],
                                     fmaf(xa[u + 3], wb[3 * rra + 2], acc[py][u])));
                }
                const int rrb = 2 * rp - py;
                if (rrb >= 0 && rrb <= 2) {
#pragma unroll
                    for (int u = 0; u < 2; ++u)
                        acc[py][u] = fmaf(xv[u + 1], wb[3 * rrb],
                                     fmaf(xv[u + 2], wb[3 * rrb + 1],
                                     fmaf(xv[u + 3], wb[3 * rrb + 2], acc[py][u])));
                }
            }
        }

        // epilogue: per-quad IDWT + base path, pack, stats
        const float n1A = bfr2f(nxt1[n1b + (size_t)(hy0 + h0) * 128 + (hx0 + qj)]);
        const float n1B = bfr2f(nxt1[n1b + (size_t)(hy0 + h0 + 1) * 128 + (hx0 + qj)]);
        const size_t ybase = xb + (size_t)(oy0 + 4 * pair) * 256 + (ox0 + 2 * qj);
#pragma unroll
        for (int quad = 0; quad < 2; ++quad) {
            const float* kk = quad ? kkB : kkA;
            float c0 = fmaf(kk[0], sc[0], 0.5f * (quad ? n1B : n1A));
            float c1 = kk[1] * sc[1];
            float c2 = kk[2] * sc[2];
            float c3 = kk[3] * sc[3];
            float vv00 = c0 + c1 + c2 + c3;
            float vv01 = c0 + c1 - c2 - c3;
            float vv10 = c0 - c1 + c2 - c3;
            float vv11 = c0 - c1 - c2 + c3;
            float v00 = fmaf(acc[2 * quad][0],     scale, bsc) + vv00;
            float v01 = fmaf(acc[2 * quad][1],     scale, bsc) + vv01;
            float v10 = fmaf(acc[2 * quad + 1][0], scale, bsc) + vv10;
            float v11 = fmaf(acc[2 * quad + 1][1], scale, bsc) + vv11;
            lsum += v00 + v01 + v10 + v11;
            lss = fmaf(v00, v00, lss); lss = fmaf(v01, v01, lss);
            lss = fmaf(v10, v10, lss); lss = fmaf(v11, v11, lss);
            *(unsigned*)(ybf + ybase + (size_t)(2 * quad) * 256)     = cvt_pk_bf16(v00, v01);
            *(unsigned*)(ybf + ybase + (size_t)(2 * quad + 1) * 256) = cvt_pk_bf16(v10, v11);
        }
    }

    // wave shuffle reduce, then 4 wave partials via LDS
#pragma unroll
    for (int off = 32; off > 0; off >>= 1) {
        lsum += __shfl_xor(lsum, off);
        lss  += __shfl_xor(lss, off);
    }
    if ((tid & 63) == 0) sW4[tid >> 6] = make_float2(lsum, lss);
    __syncthreads();
    if (tid == 0) {
        float s = sW4[0].x + sW4[1].x + sW4[2].x + sW4[3].x;
        float q = sW4[0].y + sW4[1].y + sW4[2].y + sW4[3].y;
        partials[c * 256 + b * 16 + tile] = make_float2(s, q);
    }
}

// ---------------------------------------------------------------------------
// K7: per-channel BN stats -> (a,b). 64 blocks x 256 threads.
// ---------------------------------------------------------------------------
__global__ __launch_bounds__(256) void stats_kernel(
    const float2* __restrict__ partials, const float* __restrict__ gamma,
    const float* __restrict__ beta, float2* __restrict__ ab)
{
    const int c = blockIdx.x;
    const int tid = threadIdx.x;
    __shared__ float s1[256], s2[256];
    float2 p = partials[c * 256 + tid];
    s1[tid] = p.x;
    s2[tid] = p.y;
    __syncthreads();
    for (int off = 128; off > 0; off >>= 1) {
        if (tid < off) { s1[tid] += s1[tid + off]; s2[tid] += s2[tid + off]; }
        __syncthreads();
    }
    if (tid == 0) {
        const float N = (float)NB * 65536.0f;
        float mean = s1[0] / N;
        float var = s2[0] / N - mean * mean;
        float inv = rsqrtf(var + 1e-5f);
        float a = gamma[c] * inv;
        ab[c] = make_float2(a, beta[c] - mean * a);
    }
}

// ---------------------------------------------------------------------------
// K8: normalize + ReLU: bf16 y-staging -> fp32 d_out. 8 elems per iter.
// ---------------------------------------------------------------------------
__global__ __launch_bounds__(256) void norm_out_kernel(
    const unsigned short* __restrict__ ybf, const float2* __restrict__ ab,
    float* __restrict__ out)
{
    const long total8 = (long)NB * NC * 65536 / 8;
    const long stride = (long)gridDim.x * 256;
    for (long i = blockIdx.x * 256L + threadIdx.x; i < total8; i += stride) {
        long e = i * 8;
        int c = (int)((e >> 16) & (NC - 1));
        float2 s = ab[c];
        uint4 v = *(const uint4*)(ybf + e);
        float4 o0, o1;
        o0.x = fmaxf(fmaf(bfr2f((unsigned short)(v.x & 0xffff)), s.x, s.y), 0.f);
        o0.y = fmaxf(fmaf(bfr2f((unsigned short)(v.x >> 16)),    s.x, s.y), 0.f);
        o0.z = fmaxf(fmaf(bfr2f((unsigned short)(v.y & 0xffff)), s.x, s.y), 0.f);
        o0.w = fmaxf(fmaf(bfr2f((unsigned short)(v.y >> 16)),    s.x, s.y), 0.f);
        o1.x = fmaxf(fmaf(bfr2f((unsigned short)(v.z & 0xffff)), s.x, s.y), 0.f);
        o1.y = fmaxf(fmaf(bfr2f((unsigned short)(v.z >> 16)),    s.x, s.y), 0.f);
        o1.z = fmaxf(fmaf(bfr2f((unsigned short)(v.w & 0xffff)), s.x, s.y), 0.f);
        o1.w = fmaxf(fmaf(bfr2f((unsigned short)(v.w >> 16)),    s.x, s.y), 0.f);
        *(float4*)(out + e) = o0;
        *(float4*)(out + e + 4) = o1;
    }
}

extern "C" void kernel_launch(void* const* d_in, const int* in_sizes, int n_in,
                              void* d_out, int out_size, void* d_ws, size_t ws_size,
                              hipStream_t stream)
{
    const float* x    = (const float*)d_in[0];
    const float* bw   = (const float*)d_in[1];
    const float* bb   = (const float*)d_in[2];
    const float* bs   = (const float*)d_in[3];
    const float* ww0  = (const float*)d_in[4];
    const float* ww1  = (const float*)d_in[5];
    const float* ww2  = (const float*)d_in[6];
    const float* ws0  = (const float*)d_in[7];
    const float* ws1  = (const float*)d_in[8];
    const float* ws2  = (const float*)d_in[9];
    const float* gamma = (const float*)d_in[10];
    const float* beta  = (const float*)d_in[11];

    char* w = (char*)d_ws;
    unsigned short* ybf  = (unsigned short*)(w);                   // 134.2 MB (born K6)
    unsigned short* t1   = (unsigned short*)(w + 134217728);       // 33.6 MB bf16
    float*          cur2 = (float*)(w + 167772160);                // 16.8 MB fp32
    unsigned short* t2   = (unsigned short*)(w + 184549376);       // 8.4 MB bf16
    unsigned short* nxt1 = (unsigned short*)(w + 192937984);       // 33.6 MB bf16
    float2*         partials = (float2*)(w + 226492416);           // 128 KB
    float2*         ab       = (float2*)(w + 226623488);

    // K2': level 1 directly from x (LL computed in LDS; old K1 fused away)
    dwt_conv_from_x_kernel<<<dim3(4, NC, NB), 256, 0, stream>>>(x, ww1, ws1, t1, cur2);
    // K3: level 2
    dwt_conv_kernel64<<<dim3(1, NC, NB), 256, 0, stream>>>(cur2, ww2, ws2, t2);
    // K45: fused recon level2+1 -> nxt1 (all bf16)
    idwt_fuse_kernel<<<dim3(NB * NC * 4096 / 256), 256, 0, stream>>>(t1, t2, nxt1);
    // K6: base conv + level-0 dwt/conv/idwt -> ybf (bf16) + partials
    final_fuse_kernel<<<dim3(16, NC, NB), 256, 0, stream>>>(x, nxt1, bw, bb, bs, ww0, ws0, ybf, partials);
    // K7: BN stats
    stats_kernel<<<dim3(64), 256, 0, stream>>>(partials, gamma, beta, ab);
    // K8: normalize + relu -> d_out (fp32)
    norm_out_kernel<<<dim3(2048), 256, 0, stream>>>(ybf, ab, (float*)d_out);
}

// Round 10
// 301.824 us; speedup vs baseline: 1.3623x; 1.0492x over previous
//
#include <hip/hip_runtime.h>
#include <hip/hip_bf16.h>

#define NB 16
#define NC 64

static __device__ __forceinline__ float bfr2f(unsigned short h) {
    union { unsigned u; float f; } cv; cv.u = ((unsigned)h) << 16;
    return cv.f;
}
// 1-instruction packed fp32->bf16 (RNE) [gfx950 v_cvt_pk_bf16_f32]
static __device__ __forceinline__ unsigned cvt_pk_bf16(float lo, float hi) {
    unsigned r;
    asm("v_cvt_pk_bf16_f32 %0, %1, %2" : "=v"(r) : "v"(lo), "v"(hi));
    return r;
}

// ---------------------------------------------------------------------------
// Shift-addressed float4 staging of a 68-row x 72-col halo tile, stride 72.
// ---------------------------------------------------------------------------
template <int H>
static __device__ __forceinline__ void stage_tile(
    const float* __restrict__ src, size_t ibase, int sTop, int sLeft,
    float (*sIn)[72], int tid)
{
#pragma unroll
    for (int i = 0; i < 5; ++i) {
        int idx = i * 256 + tid;
        if (idx < 68 * 16) {
            int r = idx >> 4, c4 = (idx & 15) << 2;
            int gy = sTop + r, gx = sLeft + c4;
            float4 v = make_float4(0.f, 0.f, 0.f, 0.f);
            if ((unsigned)gy < (unsigned)H && (unsigned)gx < (unsigned)H)
                v = *(const float4*)(src + ibase + (size_t)gy * H + gx);
            *(float4*)(&sIn[r][c4]) = v;
        }
    }
    if (tid < 136) {
        int r = tid >> 1, c4 = 64 + ((tid & 1) << 2);
        int gy = sTop + r, gx = sLeft + c4;
        float4 v = make_float4(0.f, 0.f, 0.f, 0.f);
        if ((unsigned)gy < (unsigned)H && (unsigned)gx < (unsigned)H)
            v = *(const float4*)(src + ibase + (size_t)gy * H + gx);
        *(float4*)(&sIn[r][c4]) = v;
    }
}

// ---------------------------------------------------------------------------
// Shared compute: level DWT + 4 band convs on a staged 68x72 tile.
// 2x2 outputs/thread at (qi+mi, qj+mj); kk[band][2*mi+mj] UNSCALED.
// llc = pre-conv LL (x0.5) at the 4 output positions.
// ---------------------------------------------------------------------------
static __device__ __forceinline__ void dwt_conv_compute(
    const float (*sIn)[72], const float w[4][9], float kk[4][4], float llc[4],
    int qi, int qj)
{
#pragma unroll
    for (int i = 0; i < 4; ++i)
#pragma unroll
        for (int j = 0; j < 4; ++j) kk[i][j] = 0.f;

    const int pr0 = 2 * qi, pc0 = 2 * qj + 2;
#pragma unroll
    for (int rp = 0; rp < 4; ++rp) {
        float xa[8], xb[8];
#pragma unroll
        for (int n = 0; n < 4; ++n) {
            float2 va = *(const float2*)&sIn[pr0 + 2 * rp][pc0 + 2 * n];
            float2 vb = *(const float2*)&sIn[pr0 + 2 * rp + 1][pc0 + 2 * n];
            xa[2 * n] = va.x; xa[2 * n + 1] = va.y;
            xb[2 * n] = vb.x; xb[2 * n + 1] = vb.y;
        }
        float D0[4], D1[4], D2[4], D3[4];
#pragma unroll
        for (int n = 0; n < 4; ++n) {
            float a = xa[2 * n], e = xa[2 * n + 1];
            float f = xb[2 * n], g = xb[2 * n + 1];
            float s0 = a + e, s1 = f + g, d0 = a - e, d1 = f - g;
            D0[n] = s0 + s1; D1[n] = s0 - s1;
            D2[n] = d0 + d1; D3[n] = d0 - d1;
        }
#pragma unroll
        for (int mi = 0; mi < 2; ++mi) {
            const int r = rp - mi;
            if (r >= 0 && r <= 2) {
#pragma unroll
                for (int mj = 0; mj < 2; ++mj) {
                    const int m = 2 * mi + mj;
#pragma unroll
                    for (int s = 0; s < 3; ++s) {
                        kk[0][m] = fmaf(w[0][3 * r + s], D0[mj + s], kk[0][m]);
                        kk[1][m] = fmaf(w[1][3 * r + s], D1[mj + s], kk[1][m]);
                        kk[2][m] = fmaf(w[2][3 * r + s], D2[mj + s], kk[2][m]);
                        kk[3][m] = fmaf(w[3][3 * r + s], D3[mj + s], kk[3][m]);
                    }
                }
                if (r == 1) {
                    llc[2 * mi + 0] = 0.5f * D0[1];
                    llc[2 * mi + 1] = 0.5f * D0[2];
                }
            }
        }
    }
}

// ---------------------------------------------------------------------------
// K2': level-1 DWT+conv with the LL halo computed DIRECTLY from x.
// Writes t1 (bf16 bands) + cur2 (fp32 LL2).
// ---------------------------------------------------------------------------
__global__ __launch_bounds__(256) void dwt_conv_from_x_kernel(
    const float* __restrict__ x, const float* __restrict__ ww,
    const float* __restrict__ wsc, unsigned short* __restrict__ t_out,
    float* __restrict__ curn)
{
    const int tile = blockIdx.x;            // 4 tiles (2x2) of 32x32 @64-res
    const int c = blockIdx.y, b = blockIdx.z;
    const int ty = tile >> 1, tx = tile & 1;
    const int oy0 = ty * 32, ox0 = tx * 32;
    const int tid = threadIdx.x;
    const int qi = 2 * (tid >> 4), qj = 2 * (tid & 15);

    __shared__ float sLL[68][72];

    float w[4][9], sc[4];
#pragma unroll
    for (int k = 0; k < 4; ++k) {
#pragma unroll
        for (int i = 0; i < 9; ++i) w[k][i] = ww[(c * 4 + k) * 9 + i];
        sc[k] = 0.5f * wsc[c * 4 + k];
    }

    const size_t xbase = (size_t)(b * NC + c) * 65536;
    const int gy0 = 4 * oy0 - 4;
    const int gx0 = 4 * ox0 - 8;
    for (int u = tid; u < 68 * 36; u += 256) {
        int r = u / 36, cp = u - r * 36;
        int gy = gy0 + 2 * r, gx = gx0 + 4 * cp;
        float4 va = make_float4(0.f, 0.f, 0.f, 0.f);
        float4 vb = va;
        if ((unsigned)gy < 256u && (unsigned)gx < 256u) {
            va = *(const float4*)(x + xbase + (size_t)gy * 256 + gx);
            vb = *(const float4*)(x + xbase + (size_t)(gy + 1) * 256 + gx);
        }
        *(float2*)(&sLL[r][2 * cp]) =
            make_float2(0.5f * (va.x + va.y + vb.x + vb.y),
                        0.5f * (va.z + va.w + vb.z + vb.w));
    }
    __syncthreads();

    float kk[4][4], llc[4];
    dwt_conv_compute(sLL, w, kk, llc, qi, qj);

    const size_t tbase = (size_t)(b * NC + c) * 4 * 4096;
    const size_t o00 = (size_t)(oy0 + qi) * 64 + (ox0 + qj);
#pragma unroll
    for (int band = 0; band < 4; ++band) {
        size_t bo = tbase + (size_t)band * 4096 + o00;
#pragma unroll
        for (int mi = 0; mi < 2; ++mi)
            *(unsigned*)(t_out + bo + (size_t)mi * 64) =
                cvt_pk_bf16(kk[band][2 * mi] * sc[band], kk[band][2 * mi + 1] * sc[band]);
    }
    const size_t cbase = (size_t)(b * NC + c) * 4096 + o00;
    *(float2*)(curn + cbase)      = make_float2(llc[0], llc[1]);
    *(float2*)(curn + cbase + 64) = make_float2(llc[2], llc[3]);
}

// ---------------------------------------------------------------------------
// K3': level-2 DWT+conv (t2 kept in REGISTERS) fused with the 2-level IDWT
// reconstruction: nxt1 = idwt(t1 with LL += idwt(t2)). One block per image.
// ---------------------------------------------------------------------------
__global__ __launch_bounds__(256) void level2_recon_kernel(
    const float* __restrict__ cur2, const float* __restrict__ ww,
    const float* __restrict__ wsc, const unsigned short* __restrict__ t1,
    unsigned short* __restrict__ nxt1)
{
    const int c = blockIdx.y, b = blockIdx.z;
    const int tid = threadIdx.x;
    const int qi = 2 * (tid >> 4), qj = 2 * (tid & 15);

    __shared__ float sIn[68][72];

    float w[4][9], sc[4];
#pragma unroll
    for (int k = 0; k < 4; ++k) {
#pragma unroll
        for (int i = 0; i < 9; ++i) w[k][i] = ww[(c * 4 + k) * 9 + i];
        sc[k] = 0.5f * wsc[c * 4 + k];
    }

    const size_t ibase = (size_t)(b * NC + c) * 4096;
    stage_tile<64>(cur2, ibase, -2, -4, sIn, tid);
    __syncthreads();

    float kk[4][4], llc[4];
    dwt_conv_compute(sIn, w, kk, llc, qi, qj);
#pragma unroll
    for (int band = 0; band < 4; ++band)
#pragma unroll
        for (int m = 0; m < 4; ++m) kk[band][m] *= sc[band];

    // recon: thread's t2 quad -> nxt2 4x4 (64-res) -> nxt1 8x8 (128-res)
    const size_t img = (size_t)(b * NC + c);
    const unsigned short* t1p = t1 + img * 16384;
    unsigned short* n1p = nxt1 + img * 16384;
#pragma unroll
    for (int di = 0; di < 4; ++di) {
        const int i1 = 2 * qi + di;
        const int col = 2 * qj;               // qj even -> 8B aligned
        uint2 r0 = *(const uint2*)(t1p +              (size_t)i1 * 64 + col);
        uint2 r1 = *(const uint2*)(t1p + 4096 +  (size_t)i1 * 64 + col);
        uint2 r2 = *(const uint2*)(t1p + 8192 +  (size_t)i1 * 64 + col);
        uint2 r3 = *(const uint2*)(t1p + 12288 + (size_t)i1 * 64 + col);
        float v0[4] = { bfr2f((unsigned short)(r0.x & 0xffff)), bfr2f((unsigned short)(r0.x >> 16)),
                        bfr2f((unsigned short)(r0.y & 0xffff)), bfr2f((unsigned short)(r0.y >> 16)) };
        float v1[4] = { bfr2f((unsigned short)(r1.x & 0xffff)), bfr2f((unsigned short)(r1.x >> 16)),
                        bfr2f((unsigned short)(r1.y & 0xffff)), bfr2f((unsigned short)(r1.y >> 16)) };
        float v2[4] = { bfr2f((unsigned short)(r2.x & 0xffff)), bfr2f((unsigned short)(r2.x >> 16)),
                        bfr2f((unsigned short)(r2.y & 0xffff)), bfr2f((unsigned short)(r2.y >> 16)) };
        float v3[4] = { bfr2f((unsigned short)(r3.x & 0xffff)), bfr2f((unsigned short)(r3.x >> 16)),
                        bfr2f((unsigned short)(r3.y & 0xffff)), bfr2f((unsigned short)(r3.y >> 16)) };
        float top[8], bot[8];
#pragma unroll
        for (int dj = 0; dj < 4; ++dj) {
            const int m = 2 * (di >> 1) + (dj >> 1);
            float m0 = kk[0][m], m1 = kk[1][m], m2 = kk[2][m], m3 = kk[3][m];
            float s1v = (di & 1) ? -m1 : m1;
            float s2v = (dj & 1) ? -m2 : m2;
            float s3v = ((di ^ dj) & 1) ? -m3 : m3;
            float k0 = v0[dj] + 0.5f * (m0 + s1v + s2v + s3v);
            float k1 = v1[dj], k2 = v2[dj], k3 = v3[dj];
            top[2 * dj]     = 0.5f * (k0 + k1 + k2 + k3);
            top[2 * dj + 1] = 0.5f * (k0 + k1 - k2 - k3);
            bot[2 * dj]     = 0.5f * (k0 - k1 + k2 - k3);
            bot[2 * dj + 1] = 0.5f * (k0 - k1 - k2 + k3);
        }
        const size_t ob = (size_t)(4 * qi + 2 * di) * 128 + 4 * qj;  // 16B aligned
        uint4 tv, bv;
        tv.x = cvt_pk_bf16(top[0], top[1]); tv.y = cvt_pk_bf16(top[2], top[3]);
        tv.z = cvt_pk_bf16(top[4], top[5]); tv.w = cvt_pk_bf16(top[6], top[7]);
        bv.x = cvt_pk_bf16(bot[0], bot[1]); bv.y = cvt_pk_bf16(bot[2], bot[3]);
        bv.z = cvt_pk_bf16(bot[4], bot[5]); bv.w = cvt_pk_bf16(bot[6], bot[7]);
        *(uint4*)(n1p + ob) = tv;
        *(uint4*)(n1p + ob + 128) = bv;
    }
}

// ---------------------------------------------------------------------------
// K6: final fuse, vertical quad-pair version (round-9 structure) with
// nxt1 prefetch issued before the barrier and stride-72 LDS (8 blocks/CU).
// ---------------------------------------------------------------------------
__global__ __launch_bounds__(256) void final_fuse_kernel(
    const float* __restrict__ x, const unsigned short* __restrict__ nxt1,
    const float* __restrict__ bw, const float* __restrict__ bb,
    const float* __restrict__ bs, const float* __restrict__ ww0,
    const float* __restrict__ ws0,
    unsigned short* __restrict__ ybf, float2* __restrict__ partials)
{
    const int tile = blockIdx.x, c = blockIdx.y, b = blockIdx.z;
    const int ty = tile >> 2, tx = tile & 3;
    const int oy0 = ty * 64, ox0 = tx * 64;
    const int hy0 = ty * 32, hx0 = tx * 32;
    const int tid = threadIdx.x;
    const int qj = tid & 31;
    const int pr = tid >> 5;

    __shared__ float sIn[68][72];
    __shared__ float2 sW4[4];

    float w[4][9], sc[4], wb[9];
#pragma unroll
    for (int k = 0; k < 4; ++k) {
#pragma unroll
        for (int i = 0; i < 9; ++i) w[k][i] = ww0[(c * 4 + k) * 9 + i];
        sc[k] = 0.25f * ws0[c * 4 + k];
    }
#pragma unroll
    for (int i = 0; i < 9; ++i) wb[i] = bw[c * 9 + i];
    const float scale = bs[c];
    const float bsc = bb[c] * scale;

    const size_t xb = (size_t)(b * NC + c) * 65536;
    stage_tile<256>(x, xb, oy0 - 2, ox0 - 4, sIn, tid);

    // prefetch all 4 nxt1 values (T14 issue-early: latency hides under
    // LDS staging + barrier)
    const size_t n1b = (size_t)(b * NC + c) * 16384 + hx0 + qj;
    const float n1p0A = bfr2f(nxt1[n1b + (size_t)(hy0 + 2 * pr) * 128]);
    const float n1p0B = bfr2f(nxt1[n1b + (size_t)(hy0 + 2 * pr + 1) * 128]);
    const float n1p1A = bfr2f(nxt1[n1b + (size_t)(hy0 + 2 * pr + 16) * 128]);
    const float n1p1B = bfr2f(nxt1[n1b + (size_t)(hy0 + 2 * pr + 17) * 128]);

    __syncthreads();

    float lsum = 0.f, lss = 0.f;

#pragma unroll
    for (int pass = 0; pass < 2; ++pass) {
        const int pair = pr + 8 * pass;
        const int prow0 = 4 * pair;
        const int pc0 = 2 * qj + 2;

        float kkA[4], kkB[4];
#pragma unroll
        for (int k = 0; k < 4; ++k) { kkA[k] = 0.f; kkB[k] = 0.f; }
        float acc[4][2];
#pragma unroll
        for (int p = 0; p < 4; ++p) { acc[p][0] = 0.f; acc[p][1] = 0.f; }

#pragma unroll
        for (int rp = 0; rp < 4; ++rp) {
            float xa[6], xv[6];
#pragma unroll
            for (int n = 0; n < 3; ++n) {
                float2 va = *(const float2*)&sIn[prow0 + 2 * rp][pc0 + 2 * n];
                float2 vb = *(const float2*)&sIn[prow0 + 2 * rp + 1][pc0 + 2 * n];
                xa[2 * n] = va.x; xa[2 * n + 1] = va.y;
                xv[2 * n] = vb.x; xv[2 * n + 1] = vb.y;
            }
            float D0[3], D1[3], D2[3], D3[3];
#pragma unroll
            for (int n = 0; n < 3; ++n) {
                float a = xa[2 * n], e = xa[2 * n + 1];
                float f = xv[2 * n], g = xv[2 * n + 1];
                float s0 = a + e, s1 = f + g, d0 = a - e, d1 = f - g;
                D0[n] = s0 + s1; D1[n] = s0 - s1;
                D2[n] = d0 + d1; D3[n] = d0 - d1;
            }
            if (rp <= 2) {
#pragma unroll
                for (int s = 0; s < 3; ++s) {
                    kkA[0] = fmaf(w[0][3 * rp + s], D0[s], kkA[0]);
                    kkA[1] = fmaf(w[1][3 * rp + s], D1[s], kkA[1]);
                    kkA[2] = fmaf(w[2][3 * rp + s], D2[s], kkA[2]);
                    kkA[3] = fmaf(w[3][3 * rp + s], D3[s], kkA[3]);
                }
            }
            if (rp >= 1) {
                const int r = rp - 1;
#pragma unroll
                for (int s = 0; s < 3; ++s) {
                    kkB[0] = fmaf(w[0][3 * r + s], D0[s], kkB[0]);
                    kkB[1] = fmaf(w[1][3 * r + s], D1[s], kkB[1]);
                    kkB[2] = fmaf(w[2][3 * r + s], D2[s], kkB[2]);
                    kkB[3] = fmaf(w[3][3 * r + s], D3[s], kkB[3]);
                }
            }
#pragma unroll
            for (int py = 0; py < 4; ++py) {
                const int rra = 2 * rp - py - 1;
                if (rra >= 0 && rra <= 2) {
#pragma unroll
                    for (int u = 0; u < 2; ++u)
                        acc[py][u] = fmaf(xa[u + 1], wb[3 * rra],
                                     fmaf(xa[u + 2], wb[3 * rra + 1],
                                     fmaf(xa[u + 3], wb[3 * rra + 2], acc[py][u])));
                }
                const int rrb = 2 * rp - py;
                if (rrb >= 0 && rrb <= 2) {
#pragma unroll
                    for (int u = 0; u < 2; ++u)
                        acc[py][u] = fmaf(xv[u + 1], wb[3 * rrb],
                                     fmaf(xv[u + 2], wb[3 * rrb + 1],
                                     fmaf(xv[u + 3], wb[3 * rrb + 2], acc[py][u])));
                }
            }
        }

        const float n1A = pass ? n1p1A : n1p0A;
        const float n1B = pass ? n1p1B : n1p0B;
        const size_t ybase = xb + (size_t)(oy0 + 4 * pair) * 256 + (ox0 + 2 * qj);
#pragma unroll
        for (int quad = 0; quad < 2; ++quad) {
            const float* kk = quad ? kkB : kkA;
            float c0 = fmaf(kk[0], sc[0], 0.5f * (quad ? n1B : n1A));
            float c1 = kk[1] * sc[1];
            float c2 = kk[2] * sc[2];
            float c3 = kk[3] * sc[3];
            float vv00 = c0 + c1 + c2 + c3;
            float vv01 = c0 + c1 - c2 - c3;
            float vv10 = c0 - c1 + c2 - c3;
            float vv11 = c0 - c1 - c2 + c3;
            float v00 = fmaf(acc[2 * quad][0],     scale, bsc) + vv00;
            float v01 = fmaf(acc[2 * quad][1],     scale, bsc) + vv01;
            float v10 = fmaf(acc[2 * quad + 1][0], scale, bsc) + vv10;
            float v11 = fmaf(acc[2 * quad + 1][1], scale, bsc) + vv11;
            lsum += v00 + v01 + v10 + v11;
            lss = fmaf(v00, v00, lss); lss = fmaf(v01, v01, lss);
            lss = fmaf(v10, v10, lss); lss = fmaf(v11, v11, lss);
            *(unsigned*)(ybf + ybase + (size_t)(2 * quad) * 256)     = cvt_pk_bf16(v00, v01);
            *(unsigned*)(ybf + ybase + (size_t)(2 * quad + 1) * 256) = cvt_pk_bf16(v10, v11);
        }
    }

#pragma unroll
    for (int off = 32; off > 0; off >>= 1) {
        lsum += __shfl_xor(lsum, off);
        lss  += __shfl_xor(lss, off);
    }
    if ((tid & 63) == 0) sW4[tid >> 6] = make_float2(lsum, lss);
    __syncthreads();
    if (tid == 0) {
        float s = sW4[0].x + sW4[1].x + sW4[2].x + sW4[3].x;
        float q = sW4[0].y + sW4[1].y + sW4[2].y + sW4[3].y;
        partials[c * 256 + b * 16 + tile] = make_float2(s, q);
    }
}

// ---------------------------------------------------------------------------
// K7: per-channel BN stats -> (a,b). 64 blocks x 256 threads.
// ---------------------------------------------------------------------------
__global__ __launch_bounds__(256) void stats_kernel(
    const float2* __restrict__ partials, const float* __restrict__ gamma,
    const float* __restrict__ beta, float2* __restrict__ ab)
{
    const int c = blockIdx.x;
    const int tid = threadIdx.x;
    __shared__ float s1[256], s2[256];
    float2 p = partials[c * 256 + tid];
    s1[tid] = p.x;
    s2[tid] = p.y;
    __syncthreads();
    for (int off = 128; off > 0; off >>= 1) {
        if (tid < off) { s1[tid] += s1[tid + off]; s2[tid] += s2[tid + off]; }
        __syncthreads();
    }
    if (tid == 0) {
        const float N = (float)NB * 65536.0f;
        float mean = s1[0] / N;
        float var = s2[0] / N - mean * mean;
        float inv = rsqrtf(var + 1e-5f);
        float a = gamma[c] * inv;
        ab[c] = make_float2(a, beta[c] - mean * a);
    }
}

// ---------------------------------------------------------------------------
// K8: normalize + ReLU: bf16 y-staging -> fp32 d_out. 8 elems per iter.
// ---------------------------------------------------------------------------
__global__ __launch_bounds__(256) void norm_out_kernel(
    const unsigned short* __restrict__ ybf, const float2* __restrict__ ab,
    float* __restrict__ out)
{
    const long total8 = (long)NB * NC * 65536 / 8;
    const long stride = (long)gridDim.x * 256;
    for (long i = blockIdx.x * 256L + threadIdx.x; i < total8; i += stride) {
        long e = i * 8;
        int c = (int)((e >> 16) & (NC - 1));
        float2 s = ab[c];
        uint4 v = *(const uint4*)(ybf + e);
        float4 o0, o1;
        o0.x = fmaxf(fmaf(bfr2f((unsigned short)(v.x & 0xffff)), s.x, s.y), 0.f);
        o0.y = fmaxf(fmaf(bfr2f((unsigned short)(v.x >> 16)),    s.x, s.y), 0.f);
        o0.z = fmaxf(fmaf(bfr2f((unsigned short)(v.y & 0xffff)), s.x, s.y), 0.f);
        o0.w = fmaxf(fmaf(bfr2f((unsigned short)(v.y >> 16)),    s.x, s.y), 0.f);
        o1.x = fmaxf(fmaf(bfr2f((unsigned short)(v.z & 0xffff)), s.x, s.y), 0.f);
        o1.y = fmaxf(fmaf(bfr2f((unsigned short)(v.z >> 16)),    s.x, s.y), 0.f);
        o1.z = fmaxf(fmaf(bfr2f((unsigned short)(v.w & 0xffff)), s.x, s.y), 0.f);
        o1.w = fmaxf(fmaf(bfr2f((unsigned short)(v.w >> 16)),    s.x, s.y), 0.f);
        *(float4*)(out + e) = o0;
        *(float4*)(out + e + 4) = o1;
    }
}

extern "C" void kernel_launch(void* const* d_in, const int* in_sizes, int n_in,
                              void* d_out, int out_size, void* d_ws, size_t ws_size,
                              hipStream_t stream)
{
    const float* x    = (const float*)d_in[0];
    const float* bw   = (const float*)d_in[1];
    const float* bb   = (const float*)d_in[2];
    const float* bs   = (const float*)d_in[3];
    const float* ww0  = (const float*)d_in[4];
    const float* ww1  = (const float*)d_in[5];
    const float* ww2  = (const float*)d_in[6];
    const float* ws0  = (const float*)d_in[7];
    const float* ws1  = (const float*)d_in[8];
    const float* ws2  = (const float*)d_in[9];
    const float* gamma = (const float*)d_in[10];
    const float* beta  = (const float*)d_in[11];

    char* w = (char*)d_ws;
    unsigned short* ybf  = (unsigned short*)(w);                   // 134.2 MB (born K6)
    unsigned short* t1   = (unsigned short*)(w + 134217728);       // 33.6 MB bf16
    float*          cur2 = (float*)(w + 167772160);                // 16.8 MB fp32
    unsigned short* nxt1 = (unsigned short*)(w + 184549376);       // 33.6 MB bf16
    float2*         partials = (float2*)(w + 218103808);           // 128 KB
    float2*         ab       = (float2*)(w + 218234880);

    // K2': level 1 directly from x (LL computed in LDS)
    dwt_conv_from_x_kernel<<<dim3(4, NC, NB), 256, 0, stream>>>(x, ww1, ws1, t1, cur2);
    // K3': level 2 bands in registers + fused 2-level recon -> nxt1
    level2_recon_kernel<<<dim3(1, NC, NB), 256, 0, stream>>>(cur2, ww2, ws2, t1, nxt1);
    // K6: base conv + level-0 dwt/conv/idwt -> ybf (bf16) + partials
    final_fuse_kernel<<<dim3(16, NC, NB), 256, 0, stream>>>(x, nxt1, bw, bb, bs, ww0, ws0, ybf, partials);
    // K7: BN stats
    stats_kernel<<<dim3(64), 256, 0, stream>>>(partials, gamma, beta, ab);
    // K8: normalize + relu -> d_out (fp32)
    norm_out_kernel<<<dim3(2048), 256, 0, stream>>>(ybf, ab, (float*)d_out);
}